// Round 3
// baseline (211.147 us; speedup 1.0000x reference)
//
#include <hip/hip_runtime.h>
#include <hip/hip_bf16.h>

#define DIMC 384          // C
#define LL 785            // 1 + 28*28
#define FDIM 1536         // 4*C  (GEMM K)
#define ODIM 768          // 2*C  (GEMM N)
#define NPATCH 196        // 14*14
#define MROWS 12544       // B*196 (GEMM M)
#define BATCH 64

typedef __attribute__((ext_vector_type(8))) short bf16x8;
typedef __attribute__((ext_vector_type(4))) float floatx4;
typedef __attribute__((ext_vector_type(4))) unsigned short ushort4v;

// ws layout (bytes):
//   anorm u16[12544*1536] @ 0           (38,535,168 B)  pre-normalized bf16 A
//   wbf   u16[768*1536]   @ 38535168    ( 2,359,296 B)  bf16(gamma * w_red)
//   bias  f32[768]        @ 40894464    (     3,072 B)  sum_f beta*w_red
#define WS_WBF_OFF  38535168
#define WS_BIAS_OFF 40894464

// prep role bases (cls first so its L2-latency-bound blocks hide under norm)
#define PB_CLS   0
#define PB_NORM  192
#define PB_BIAS  1760    // 192 + 1568 norm blocks (2 rows/wave)
#define PB_WBF   1952    // + 192 bias blocks
#define PREP_BLOCKS 3104 // + 1152 wbf blocks

__device__ __forceinline__ unsigned short f2bf(float f) {
  union { float f; unsigned int u; } v; v.f = f;
  unsigned int u = v.u + 0x7fffu + ((v.u >> 16) & 1u);   // RNE
  return (unsigned short)(u >> 16);
}

__device__ __forceinline__ void gload_lds16(const void* g, void* l) {
  __builtin_amdgcn_global_load_lds(
      (const __attribute__((address_space(1))) unsigned int*)g,
      (__attribute__((address_space(3))) unsigned int*)l, 16, 0, 0);
}

// ---------------------------------------------------------------------------
// Prep kernel. Norm: 2 rows per wave (VGPR ~96 -> ~5 waves/SIMD, 6272 waves
// chip-wide so more waves are in their load-burst phase at any instant).
//   pass A: 12 independent float4 loads, values HELD in VGPRs.
//   butterfly: 2 rows x {s,s2} interleaved -> ILP-4, serial depth 6.
//   pass B: normalize held values, cvt bf16, store (pure store stream).
// ---------------------------------------------------------------------------
__global__ __launch_bounds__(256) void prep_kernel(
    const float* __restrict__ x, const float* __restrict__ wred,
    const float* __restrict__ wconv, const float* __restrict__ gamma,
    const float* __restrict__ beta, unsigned short* __restrict__ anorm,
    unsigned short* __restrict__ wbf, float* __restrict__ bias,
    float* __restrict__ out) {
  const int blk = blockIdx.x;
  const int t = threadIdx.x;
  const int wv = t >> 6;
  const int lane = t & 63;

  if (blk >= PB_NORM && blk < PB_BIAS) {  // ---- norm: 2 rows / wave ----
    // (lane,c) -> row-invariant quadrant offset (element units)
    int radd[6];
#pragma unroll
    for (int c = 0; c < 6; ++c) {
      int f = lane * 4 + c * 256;          // 384%4==0: float4 never crosses q
      int q = f / 384;
      int cc = f - q * 384;
      radd[c] = ((q & 1) * 28 + ((q >> 1) & 1)) * DIMC + cc;
    }
    const int wvid = (blk - PB_NORM) * 4 + wv;  // 0..6271
    const int g0 = wvid * 2;                    // 2 consecutive m-rows

    unsigned bo[2];                        // 32-bit element offsets (x < 2^31)
    float4 v[2][6];
    float s[2], s2[2];
#pragma unroll
    for (int r = 0; r < 2; ++r) {          // pass A: load once, hold values
      int gw = g0 + r;
      int b = gw / NPATCH;
      int n = gw - b * NPATCH;
      int i = n / 14;
      int j = n - i * 14;
      bo[r] = (unsigned)(b * LL * DIMC + DIMC + (i * 56 + j * 2) * DIMC);
      s[r] = 0.f; s2[r] = 0.f;
#pragma unroll
      for (int c = 0; c < 6; ++c) {
        float4 vv = *reinterpret_cast<const float4*>(x + bo[r] + radd[c]);
        v[r][c] = vv;
        s[r]  += vv.x + vv.y + vv.z + vv.w;
        s2[r] += vv.x * vv.x + vv.y * vv.y + vv.z * vv.z + vv.w * vv.w;
      }
    }
#pragma unroll
    for (int o = 1; o < 64; o <<= 1) {     // 2 rows interleaved: ILP-4 chains
#pragma unroll
      for (int r = 0; r < 2; ++r) {
        s[r]  += __shfl_xor(s[r], o);
        s2[r] += __shfl_xor(s2[r], o);
      }
    }
#pragma unroll
    for (int r = 0; r < 2; ++r) {          // pass B: normalize held, store
      float mu = s[r] * (1.f / FDIM);
      float var = s2[r] * (1.f / FDIM) - mu * mu;
      float rs = rsqrtf(var + 1e-5f);
      float nmu = -mu * rs;                // a = v*rs + nmu
      unsigned short* arow = anorm + (size_t)(g0 + r) * FDIM;
#pragma unroll
      for (int c = 0; c < 6; ++c) {
        float4 vv = v[r][c];
        union { ushort4v u4; __hip_bfloat162 h[2]; } u;
        u.h[0] = __float22bfloat162_rn(
            make_float2(vv.x * rs + nmu, vv.y * rs + nmu));
        u.h[1] = __float22bfloat162_rn(
            make_float2(vv.z * rs + nmu, vv.w * rs + nmu));
        *reinterpret_cast<ushort4v*>(arow + lane * 4 + c * 256) = u.u4;
      }
    }
  } else if (blk < PB_NORM) {              // ---- cls ----
    __shared__ float xs[DIMC];
    int idx = blk;                         // < 192
    int b = idx / 3;
    int ch = idx - b * 3;
    for (int c = t; c < DIMC; c += 256) xs[c] = x[(size_t)b * LL * DIMC + c];
    __syncthreads();
    int o = ch * 256 + t;
    const float* wr = wconv + (size_t)o * DIMC;
    float a0 = 0.f, a1 = 0.f;
#pragma unroll 4
    for (int c = 0; c < DIMC; c += 8) {
      float4 w0 = *reinterpret_cast<const float4*>(wr + c);
      float4 w1 = *reinterpret_cast<const float4*>(wr + c + 4);
      float4 p0 = *reinterpret_cast<const float4*>(&xs[c]);
      float4 p1 = *reinterpret_cast<const float4*>(&xs[c + 4]);
      a0 += w0.x * p0.x + w0.y * p0.y + w0.z * p0.z + w0.w * p0.w;
      a1 += w1.x * p1.x + w1.y * p1.y + w1.z * p1.z + w1.w * p1.w;
    }
    out[(size_t)b * 197 * ODIM + o] = a0 + a1;
  } else if (blk < PB_WBF) {               // ---- bias ----
    int o = (blk - PB_BIAS) * 4 + wv;      // < 768
    const float* wr = wred + (size_t)o * FDIM;
    float s = 0.f;
#pragma unroll
    for (int c = 0; c < 6; ++c) {
      int f = lane * 4 + c * 256;
      float4 w = *reinterpret_cast<const float4*>(wr + f);
      float4 be = *reinterpret_cast<const float4*>(beta + f);
      s += w.x * be.x + w.y * be.y + w.z * be.z + w.w * be.w;
    }
#pragma unroll
    for (int o2 = 32; o2 > 0; o2 >>= 1) s += __shfl_down(s, o2);
    if (lane == 0) bias[o] = s;
  } else {                                 // ---- wbf = bf16(gamma*w_red) ----
    int idx4 = (blk - PB_WBF) * 256 + t;   // < 294912
    int e0 = idx4 * 4;
    int f = e0 % FDIM;
    float4 w = *reinterpret_cast<const float4*>(wred + e0);
    float4 g = *reinterpret_cast<const float4*>(gamma + f);
    ushort4v u;
    u.x = f2bf(w.x * g.x); u.y = f2bf(w.y * g.y);
    u.z = f2bf(w.z * g.z); u.w = f2bf(w.w * g.w);
    *reinterpret_cast<ushort4v*>(wbf + e0) = u;
  }
}

// ---------------------------------------------------------------------------
// GEMM: C[m,o] = sum_f anorm[m,f] * wbf[o,f] + bias[o].
// 128x128 tile, BK=64, 256 thr. NEW: double-buffered LDS, T3-minimum
// schedule — issue next tile's global_load_lds BEFORE computing current,
// ONE __syncthreads per K-step (its vmcnt(0) drain lands after ~250 cyc of
// MFMA, so loads fly under compute). In-block overlap matters here because
// grid is only 588 blocks (2.3/CU) with phase-synchronized blocks.
// XCD-chunked swizzle keeps the 6 same-A blocks on one XCD's L2; NT stores.
// ---------------------------------------------------------------------------
__global__ __launch_bounds__(256) void gemm_kernel(
    const unsigned short* __restrict__ anorm,
    const unsigned short* __restrict__ wbf,
    const float* __restrict__ bias, float* __restrict__ out) {
  __shared__ unsigned short As[2][128 * 64];   // 2 x 16 KB
  __shared__ unsigned short Bs[2][128 * 64];   // 2 x 16 KB

  const int t = threadIdx.x;

  // ---- chunked bijective XCD swizzle: NWG=588, q=73, r=4 ----
  const int NWG = (ODIM / 128) * (MROWS / 128);   // 588
  const int qq = NWG >> 3, rr = NWG & 7;
  int bid = blockIdx.x;
  int xcd = bid & 7, pos = bid >> 3;
  int wg = (xcd < rr) ? xcd * (qq + 1) + pos
                      : rr * (qq + 1) + (xcd - rr) * qq + pos;
  int my = wg / 6;                        // consecutive wg share my (A-panel)
  int nx = wg - my * 6;
  const int mBase = my * 128;
  const int nBase = nx * 128;

  // Staging precompute: slot s = p*256+t -> row r=s>>3, chunk c0=s&7;
  // source chunk cs = c0 ^ (r&7); LDS dest = s*16 bytes within buffer.
  const unsigned short* agp[4];
  const unsigned short* bgp[4];
  unsigned int ldsoff[4];
#pragma unroll
  for (int p = 0; p < 4; ++p) {
    int s = p * 256 + t;
    int r = s >> 3;
    int cs = (s & 7) ^ (r & 7);
    agp[p] = anorm + (size_t)(mBase + r) * FDIM + cs * 8;
    bgp[p] = wbf + (size_t)(nBase + r) * FDIM + cs * 8;
    ldsoff[p] = (unsigned)s * 8;
  }

  const int wv = t >> 6;
  const int lane = t & 63;
  const int ln15 = lane & 15;
  const int quad = lane >> 4;
  const int wm = wv >> 1;
  const int wn = wv & 1;

  unsigned int aoff[4][2], boff[4][2];
#pragma unroll
  for (int mt = 0; mt < 4; ++mt) {
#pragma unroll
    for (int h = 0; h < 2; ++h) {
      int rA = wm * 64 + mt * 16 + ln15;
      aoff[mt][h] = (unsigned)(rA * 64 + (((h * 4 + quad) ^ (rA & 7)) * 8));
      int rB = wn * 64 + mt * 16 + ln15;
      boff[mt][h] = (unsigned)(rB * 64 + (((h * 4 + quad) ^ (rB & 7)) * 8));
    }
  }

  floatx4 acc[4][4];
#pragma unroll
  for (int mt = 0; mt < 4; ++mt)
#pragma unroll
    for (int nt = 0; nt < 4; ++nt)
      acc[mt][nt] = floatx4{0.f, 0.f, 0.f, 0.f};

  // Prologue: stage tile 0 into buffer 0.
#pragma unroll
  for (int p = 0; p < 4; ++p) {
    gload_lds16(agp[p], &As[0][ldsoff[p]]);
    gload_lds16(bgp[p], &Bs[0][ldsoff[p]]);
    agp[p] += 64;
    bgp[p] += 64;
  }
  __syncthreads();                         // vmcnt(0) drain + barrier

  for (int kt = 0; kt < FDIM / 64; ++kt) {
    const int cur = kt & 1;
    const int nxt = cur ^ 1;
    if (kt < FDIM / 64 - 1) {              // issue next-tile loads FIRST
#pragma unroll
      for (int p = 0; p < 4; ++p) {
        gload_lds16(agp[p], &As[nxt][ldsoff[p]]);
        gload_lds16(bgp[p], &Bs[nxt][ldsoff[p]]);
        agp[p] += 64;
        bgp[p] += 64;
      }
    }
    // compute current tile (loads above overlap this)
#pragma unroll
    for (int h = 0; h < 2; ++h) {
      bf16x8 af[4], bfr[4];
#pragma unroll
      for (int mt = 0; mt < 4; ++mt)
        af[mt] = *reinterpret_cast<const bf16x8*>(&As[cur][aoff[mt][h]]);
#pragma unroll
      for (int nt = 0; nt < 4; ++nt)
        bfr[nt] = *reinterpret_cast<const bf16x8*>(&Bs[cur][boff[nt][h]]);
#pragma unroll
      for (int mt = 0; mt < 4; ++mt)
#pragma unroll
        for (int nt = 0; nt < 4; ++nt)
          acc[mt][nt] = __builtin_amdgcn_mfma_f32_16x16x32_bf16(
              af[mt], bfr[nt], acc[mt][nt], 0, 0, 0);
    }
    __syncthreads();  // drains vmcnt(0): next buffer ready; cur safe to reuse
  }

  // Epilogue. C/D: col = ln15, row = quad*4 + reg  [m89/m91].
  float bs[4];
#pragma unroll
  for (int nt = 0; nt < 4; ++nt)
    bs[nt] = bias[nBase + wn * 64 + nt * 16 + ln15];
#pragma unroll
  for (int mt = 0; mt < 4; ++mt) {
#pragma unroll
    for (int r = 0; r < 4; ++r) {
      int m = mBase + wm * 64 + mt * 16 + quad * 4 + r;
      int b = m / NPATCH;
      int n = m - b * NPATCH;
      float* orow = out + ((size_t)b * 197 + 1 + n) * ODIM + nBase + wn * 64;
#pragma unroll
      for (int nt = 0; nt < 4; ++nt)
        __builtin_nontemporal_store(acc[mt][nt][r] + bs[nt],
                                    &orow[nt * 16 + ln15]);
    }
  }
}

extern "C" void kernel_launch(void* const* d_in, const int* in_sizes, int n_in,
                              void* d_out, int out_size, void* d_ws, size_t ws_size,
                              hipStream_t stream) {
  const float* x     = (const float*)d_in[0];   // (64, 785, 384)
  const float* wred  = (const float*)d_in[1];   // (768, 1536)
  const float* wconv = (const float*)d_in[2];   // (768, 384)
  const float* gamma = (const float*)d_in[3];   // (1536,)
  const float* beta  = (const float*)d_in[4];   // (1536,)
  float* out = (float*)d_out;                   // (64, 197, 768)

  unsigned short* anorm = (unsigned short*)d_ws;
  unsigned short* wbf   = (unsigned short*)((char*)d_ws + WS_WBF_OFF);
  float* bias           = (float*)((char*)d_ws + WS_BIAS_OFF);

  prep_kernel<<<dim3(PREP_BLOCKS), 256, 0, stream>>>(x, wred, wconv, gamma,
                                                     beta, anorm, wbf, bias,
                                                     out);
  gemm_kernel<<<dim3((ODIM / 128) * (MROWS / 128)), 256, 0, stream>>>(
      anorm, wbf, bias, out);
}

// Round 4
// 174.088 us; speedup vs baseline: 1.2129x; 1.2129x over previous
//
#include <hip/hip_runtime.h>
#include <hip/hip_bf16.h>

#define DIMC 384          // C
#define LL 785            // 1 + 28*28
#define FDIM 1536         // 4*C  (GEMM K)
#define ODIM 768          // 2*C  (GEMM N)
#define NPATCH 196        // 14*14
#define MROWS 12544       // B*196 (GEMM M)
#define BATCH 64

typedef __attribute__((ext_vector_type(8))) short bf16x8;
typedef __attribute__((ext_vector_type(4))) float floatx4;
typedef __attribute__((ext_vector_type(4))) unsigned short ushort4v;

// ws layout (bytes):
//   xbf   u16[50176*384]  @ 0           (38,535,168 B)  bf16(raw x feature rows)
//   wbf   u16[768*1536]   @ 38535168    ( 2,359,296 B)  bf16(gamma * w_red)
//   pst   f32x2[50176]    @ 40894464    (   401,408 B)  per-(b,l) partial (s,s2)
//   bias2 f32x2[768]      @ 41295872    (     6,144 B)  (gsum, bias) per o
#define WS_WBF_OFF  38535168
#define WS_PST_OFF  40894464
#define WS_B2_OFF   41295872

// prep role bases (cls first: latency-bound blocks hide under cast stream)
#define PB_CLS   0
#define PB_CAST  192     // 3136 cast blocks (16 vectors each)
#define PB_BIAS  3328    // 192 bias blocks
#define PB_WBF   3520    // 1152 wbf blocks
#define PREP_BLOCKS 4672

__device__ __forceinline__ unsigned short f2bf(float f) {
  union { float f; unsigned int u; } v; v.f = f;
  unsigned int u = v.u + 0x7fffu + ((v.u >> 16) & 1u);   // RNE
  return (unsigned short)(u >> 16);
}

__device__ __forceinline__ void gload_lds16(const void* g, void* l) {
  __builtin_amdgcn_global_load_lds(
      (const __attribute__((address_space(1))) unsigned int*)g,
      (__attribute__((address_space(3))) unsigned int*)l, 16, 0, 0);
}

// ---------------------------------------------------------------------------
// Prep kernel.
//  cast+pstat: one (b,l) 384-float vector per QUARTER-wave. Streaming
//    x->bf16 cast (stores depend only on loads, never on stats) + per-vector
//    (s,s2) via 4-level 16-lane shfl off the store path. LayerNorm is applied
//    in the GEMM EPILOGUE (affine trick), so no butterfly blocks the stream.
//  bias2: (gsum[o], bias[o]) = (sum_f gamma*wred, sum_f beta*wred)
//  wbf:   bf16(gamma * w_red);  cls: out[b,0,:] = wconv @ x[b,0,:]
// ---------------------------------------------------------------------------
__global__ __launch_bounds__(256) void prep_kernel(
    const float* __restrict__ x, const float* __restrict__ wred,
    const float* __restrict__ wconv, const float* __restrict__ gamma,
    const float* __restrict__ beta, unsigned short* __restrict__ xbf,
    unsigned short* __restrict__ wbf, float2* __restrict__ pst,
    float2* __restrict__ bias2, float* __restrict__ out) {
  const int blk = blockIdx.x;
  const int t = threadIdx.x;
  const int wv = t >> 6;
  const int lane = t & 63;

  if (blk >= PB_CAST && blk < PB_BIAS) {  // ---- cast + partial stats ----
    const int w = (blk - PB_CAST) * 4 + wv;     // 0..12543
    const int vid = w * 4 + (lane >> 4);        // 0..50175  (b,l) vector id
    const int sub = lane & 15;
    const int b = vid / 784;
    const int ll = vid - b * 784;
    const float* src = x + ((size_t)b * LL + 1 + ll) * DIMC;
    unsigned short* dst = xbf + (size_t)vid * DIMC;
    float s = 0.f, s2 = 0.f;
#pragma unroll
    for (int c = 0; c < 6; ++c) {
      int f = sub * 4 + c * 64;
      float4 v = *reinterpret_cast<const float4*>(src + f);
      s  += v.x + v.y + v.z + v.w;
      s2 += v.x * v.x + v.y * v.y + v.z * v.z + v.w * v.w;
      union { ushort4v u4; __hip_bfloat162 h[2]; } u;
      u.h[0] = __float22bfloat162_rn(make_float2(v.x, v.y));
      u.h[1] = __float22bfloat162_rn(make_float2(v.z, v.w));
      *reinterpret_cast<ushort4v*>(dst + f) = u.u4;
    }
#pragma unroll
    for (int o = 1; o < 16; o <<= 1) {    // reduce within 16-lane group
      s  += __shfl_xor(s, o);
      s2 += __shfl_xor(s2, o);
    }
    if (sub == 0) pst[vid] = make_float2(s, s2);
  } else if (blk < PB_CAST) {              // ---- cls ----
    __shared__ float xs[DIMC];
    int idx = blk;                         // < 192
    int b = idx / 3;
    int ch = idx - b * 3;
    for (int c = t; c < DIMC; c += 256) xs[c] = x[(size_t)b * LL * DIMC + c];
    __syncthreads();
    int o = ch * 256 + t;
    const float* wr = wconv + (size_t)o * DIMC;
    float a0 = 0.f, a1 = 0.f;
#pragma unroll 4
    for (int c = 0; c < DIMC; c += 8) {
      float4 w0 = *reinterpret_cast<const float4*>(wr + c);
      float4 w1 = *reinterpret_cast<const float4*>(wr + c + 4);
      float4 p0 = *reinterpret_cast<const float4*>(&xs[c]);
      float4 p1 = *reinterpret_cast<const float4*>(&xs[c + 4]);
      a0 += w0.x * p0.x + w0.y * p0.y + w0.z * p0.z + w0.w * p0.w;
      a1 += w1.x * p1.x + w1.y * p1.y + w1.z * p1.z + w1.w * p1.w;
    }
    out[(size_t)b * 197 * ODIM + o] = a0 + a1;
  } else if (blk < PB_WBF) {               // ---- bias2 = (gsum, bias) ----
    int o = (blk - PB_BIAS) * 4 + wv;      // < 768
    const float* wr = wred + (size_t)o * FDIM;
    float sb = 0.f, sg = 0.f;
#pragma unroll
    for (int c = 0; c < 6; ++c) {
      int f = lane * 4 + c * 256;
      float4 w = *reinterpret_cast<const float4*>(wr + f);
      float4 be = *reinterpret_cast<const float4*>(beta + f);
      float4 ga = *reinterpret_cast<const float4*>(gamma + f);
      sb += w.x * be.x + w.y * be.y + w.z * be.z + w.w * be.w;
      sg += w.x * ga.x + w.y * ga.y + w.z * ga.z + w.w * ga.w;
    }
#pragma unroll
    for (int o2 = 32; o2 > 0; o2 >>= 1) {
      sb += __shfl_down(sb, o2);
      sg += __shfl_down(sg, o2);
    }
    if (lane == 0) bias2[o] = make_float2(sg, sb);
  } else {                                 // ---- wbf = bf16(gamma*w_red) ----
    int idx4 = (blk - PB_WBF) * 256 + t;   // < 294912
    int e0 = idx4 * 4;
    int f = e0 % FDIM;
    float4 w = *reinterpret_cast<const float4*>(wred + e0);
    float4 g = *reinterpret_cast<const float4*>(gamma + f);
    ushort4v u;
    u.x = f2bf(w.x * g.x); u.y = f2bf(w.y * g.y);
    u.z = f2bf(w.z * g.z); u.w = f2bf(w.w * g.w);
    *reinterpret_cast<ushort4v*>(wbf + e0) = u;
  }
}

// ---------------------------------------------------------------------------
// GEMM on RAW bf16 x (R2 proven schedule: stage / barrier / compute, 32 KB
// LDS, single buffer). A k-slice (BK=64) lies in ONE quadrant (384 = 6*64),
// so per-row source = fixed xbf row base + per-kt scalar offset dq + kk*64.
// Epilogue applies LayerNorm affinely: C = rs[m]*acc + nmu[m]*gsum[o] +
// bias[o]; per-row (rs,nmu) combined from 4 quadrant partials into LDS at
// the PROLOGUE (latency hides under the K loop).
// ---------------------------------------------------------------------------
__global__ __launch_bounds__(256) void gemm_kernel(
    const unsigned short* __restrict__ xbf,
    const unsigned short* __restrict__ wbf,
    const float2* __restrict__ pst, const float2* __restrict__ bias2,
    float* __restrict__ out) {
  __shared__ unsigned short As[128 * 64];   // 16 KB
  __shared__ unsigned short Bs[128 * 64];   // 16 KB
  __shared__ float2 st[128];                // per-row (rs, nmu)

  const int t = threadIdx.x;

  // ---- chunked bijective XCD swizzle: NWG=588, q=73, r=4 ----
  const int NWG = (ODIM / 128) * (MROWS / 128);   // 588
  const int qq = NWG >> 3, rr = NWG & 7;
  int bid = blockIdx.x;
  int xcd = bid & 7, pos = bid >> 3;
  int wg = (xcd < rr) ? xcd * (qq + 1) + pos
                      : rr * (qq + 1) + (xcd - rr) * qq + pos;
  int my = wg / 6;                        // consecutive wg share my (A-panel)
  int nx = wg - my * 6;
  const int mBase = my * 128;
  const int nBase = nx * 128;

  // Prologue stats combine: thread r<128 -> row mBase+r's (rs, nmu).
  if (t < 128) {
    int m = mBase + t;
    int b = m / NPATCH;
    int n = m - b * NPATCH;
    int i = n / 14;
    int j = n - i * 14;
    int base = b * 784 + i * 56 + j * 2;
    float2 p0 = pst[base];
    float2 p1 = pst[base + 28];
    float2 p2 = pst[base + 1];
    float2 p3 = pst[base + 29];
    float s = p0.x + p1.x + p2.x + p3.x;
    float s2 = p0.y + p1.y + p2.y + p3.y;
    float mu = s * (1.f / FDIM);
    float var = s2 * (1.f / FDIM) - mu * mu;
    float rs = rsqrtf(var + 1e-5f);
    st[t] = make_float2(rs, -mu * rs);
  }

  // Staging precompute: slot s = p*256+t -> row r=s>>3, chunk c0=s&7;
  // source chunk cs = c0 ^ (r&7); LDS dest = s*16 bytes.
  const unsigned short* agp[4];
  const unsigned short* bgp[4];
  unsigned int ldsoff[4];
#pragma unroll
  for (int p = 0; p < 4; ++p) {
    int s = p * 256 + t;
    int r = s >> 3;
    int cs = (s & 7) ^ (r & 7);
    int m = mBase + r;
    int b = m / NPATCH;
    int n = m - b * NPATCH;
    int i = n / 14;
    int j = n - i * 14;
    agp[p] = xbf + ((size_t)b * 784 + i * 56 + j * 2) * DIMC + cs * 8;
    bgp[p] = wbf + (size_t)(nBase + r) * FDIM + cs * 8;
    ldsoff[p] = (unsigned)s * 8;
  }

  const int wv = t >> 6;
  const int lane = t & 63;
  const int ln15 = lane & 15;
  const int quad = lane >> 4;
  const int wm = wv >> 1;
  const int wn = wv & 1;

  unsigned int aoff[4][2], boff[4][2];
#pragma unroll
  for (int mt = 0; mt < 4; ++mt) {
#pragma unroll
    for (int h = 0; h < 2; ++h) {
      int rA = wm * 64 + mt * 16 + ln15;
      aoff[mt][h] = (unsigned)(rA * 64 + (((h * 4 + quad) ^ (rA & 7)) * 8));
      int rB = wn * 64 + mt * 16 + ln15;
      boff[mt][h] = (unsigned)(rB * 64 + (((h * 4 + quad) ^ (rB & 7)) * 8));
    }
  }

  floatx4 acc[4][4];
#pragma unroll
  for (int mt = 0; mt < 4; ++mt)
#pragma unroll
    for (int nt = 0; nt < 4; ++nt)
      acc[mt][nt] = floatx4{0.f, 0.f, 0.f, 0.f};

  for (int kt = 0; kt < FDIM / 64; ++kt) {
    // quadrant q = kt/6 (uniform SALU), in-quadrant col kk*64
    int q = kt / 6;
    int kk = kt - q * 6;
    int ao = ((q & 1) * 28 + ((q >> 1) & 1)) * DIMC + kk * 64;
    if (kt) __syncthreads();             // all waves done reading prev tile
#pragma unroll
    for (int p = 0; p < 4; ++p) {
      gload_lds16(agp[p] + ao, &As[ldsoff[p]]);
      gload_lds16(bgp[p], &Bs[ldsoff[p]]);
      bgp[p] += 64;
    }
    __syncthreads();                     // compiler adds vmcnt(0) drain

#pragma unroll
    for (int h = 0; h < 2; ++h) {
      bf16x8 af[4], bfr[4];
#pragma unroll
      for (int mt = 0; mt < 4; ++mt)
        af[mt] = *reinterpret_cast<const bf16x8*>(&As[aoff[mt][h]]);
#pragma unroll
      for (int nt = 0; nt < 4; ++nt)
        bfr[nt] = *reinterpret_cast<const bf16x8*>(&Bs[boff[nt][h]]);
#pragma unroll
      for (int mt = 0; mt < 4; ++mt)
#pragma unroll
        for (int nt = 0; nt < 4; ++nt)
          acc[mt][nt] = __builtin_amdgcn_mfma_f32_16x16x32_bf16(
              af[mt], bfr[nt], acc[mt][nt], 0, 0, 0);
    }
  }

  // Epilogue. C/D: col = ln15, row = quad*4 + reg  [m89/m91].
  // C = rs*acc + nmu*gsum + bias.
  float2 gb[4];
#pragma unroll
  for (int nt = 0; nt < 4; ++nt)
    gb[nt] = bias2[nBase + wn * 64 + nt * 16 + ln15];
#pragma unroll
  for (int mt = 0; mt < 4; ++mt) {
#pragma unroll
    for (int r = 0; r < 4; ++r) {
      int rloc = wm * 64 + mt * 16 + quad * 4 + r;
      float2 sn = st[rloc];              // (rs, nmu)
      int m = mBase + rloc;
      int b = m / NPATCH;
      int n = m - b * NPATCH;
      float* orow = out + ((size_t)b * 197 + 1 + n) * ODIM + nBase + wn * 64;
#pragma unroll
      for (int nt = 0; nt < 4; ++nt) {
        float val = fmaf(acc[mt][nt][r], sn.x,
                         fmaf(sn.y, gb[nt].x, gb[nt].y));
        __builtin_nontemporal_store(val, &orow[nt * 16 + ln15]);
      }
    }
  }
}

extern "C" void kernel_launch(void* const* d_in, const int* in_sizes, int n_in,
                              void* d_out, int out_size, void* d_ws, size_t ws_size,
                              hipStream_t stream) {
  const float* x     = (const float*)d_in[0];   // (64, 785, 384)
  const float* wred  = (const float*)d_in[1];   // (768, 1536)
  const float* wconv = (const float*)d_in[2];   // (768, 384)
  const float* gamma = (const float*)d_in[3];   // (1536,)
  const float* beta  = (const float*)d_in[4];   // (1536,)
  float* out = (float*)d_out;                   // (64, 197, 768)

  unsigned short* xbf = (unsigned short*)d_ws;
  unsigned short* wbf = (unsigned short*)((char*)d_ws + WS_WBF_OFF);
  float2* pst         = (float2*)((char*)d_ws + WS_PST_OFF);
  float2* bias2       = (float2*)((char*)d_ws + WS_B2_OFF);

  prep_kernel<<<dim3(PREP_BLOCKS), 256, 0, stream>>>(x, wred, wconv, gamma,
                                                     beta, xbf, wbf, pst,
                                                     bias2, out);
  gemm_kernel<<<dim3((ODIM / 128) * (MROWS / 128)), 256, 0, stream>>>(
      xbf, wbf, pst, bias2, out);
}